// Round 9
// baseline (72.640 us; speedup 1.0000x reference)
//
#include <hip/hip_runtime.h>
#include <hip/hip_bf16.h>
#include <hip/hip_fp16.h>
#include <math.h>

#define HH 4
#define BB 4
#define CC 32
#define VV 1000
#define LL 12
#define EE 20000
#define NBL (BB * LL)   /* 48 */
#define SS (HH * NBL)   /* 192 */
#define RCAP 128        /* padded CSR row capacity (max deg ~45 for this input) */
#define LALPHA 0.2f
#define NEG_CAP_F -9000000000000000.0f

typedef unsigned int uint;
typedef unsigned short ushort;

// ---------------------------------------------------------------------------
// k_h (fused with scatter): blocks x<500 compute h_g/s_src/s_dst; blocks
// x>=500 do the padded-CSR scatter (cnt pre-zeroed by hipMemsetAsync).
// h_g[slab][v][c] (f16), slab=h*NBL+b*LL+l. Block = 2v x 4h x 32c.
// x rows read via wave-uniform base -> scalar (SMEM) loads, off the LDS pipe.
// ---------------------------------------------------------------------------
__global__ __launch_bounds__(256) void k_h(const float* __restrict__ x,
                                           const float* __restrict__ W,
                                           const float* __restrict__ a,
                                           ushort* __restrict__ h_g,
                                           float* __restrict__ s_src,
                                           float* __restrict__ s_dst,
                                           int* __restrict__ cnt,
                                           const int* __restrict__ ei,
                                           const float* __restrict__ ev,
                                           uint2* __restrict__ csr) {
  if (blockIdx.x >= 500) {
    // ---- scatter role: 20 x-blocks * 4 y * 256 threads = 20480 slots ----
    int e = ((blockIdx.x - 500) * 4 + blockIdx.y) * 256 + threadIdx.x;
    if (e < EE) {
      int r = ei[e];
      int d = ei[EE + e];
      int pos = atomicAdd(&cnt[r], 1);
      if (pos < RCAP) {
        float lv = fmaxf(__logf(ev[e]), NEG_CAP_F);
        csr[r * RCAP + pos] = make_uint2((uint)d, __float_as_uint(lv));
      }
    }
    return;
  }

  __shared__ float W_lds[HH * CC * CC];   // 16 KB
  __shared__ float a_lds[HH * 2 * CC];    // 1 KB
  __shared__ float x_s[CC * 2 * LL];      // 3 KB (s-part only)
  __shared__ float wa[HH][2][CC];         // 512 B
  const int tid = threadIdx.x;
  const int b = blockIdx.y;
  const int v0 = blockIdx.x * 2;

  {
    const float4* Wf = (const float4*)W;
    float4* Wl = (float4*)W_lds;
    for (int i = tid; i < HH * CC * CC / 4; i += 256) Wl[i] = Wf[i];
  }
  a_lds[tid] = a[tid];   // HH*2*CC == 256
#pragma unroll
  for (int k = 0; k < 3; ++k) {
    int i = k * 256 + tid;
    int ci = i / 24, r = i - ci * 24;
    x_s[i] = x[(b * CC + ci) * (VV * LL) + v0 * LL + r];
  }
  __syncthreads();

  // wa[h][which][ci] = sum_c W[h][ci][c]*a[h][which][c] (rotated, no conflicts)
  {
    int h = tid >> 6, which = (tid >> 5) & 1, ci = tid & 31;
    float acc = 0.f;
#pragma unroll
    for (int k = 0; k < CC; ++k) {
      int c = (k + ci) & 31;
      acc = fmaf(W_lds[h * CC * CC + ci * CC + c],
                 a_lds[h * 2 * CC + which * CC + c], acc);
    }
    wa[h][which][ci] = acc;
  }
  __syncthreads();

  const int vp = tid >> 7;          // wave-uniform (waves 0,1 -> vp0; 2,3 -> vp1)
  const int h = (tid >> 5) & 3;
  const int c = tid & 31;
  const int v = v0 + vp;

  int xoff = (b * CC) * (VV * LL) + v * LL;
  xoff = __builtin_amdgcn_readfirstlane(xoff);
  const float* xr = x + xoff;

  float acc[LL];
#pragma unroll
  for (int l = 0; l < LL; ++l) acc[l] = 0.f;

#pragma unroll 4
  for (int ci = 0; ci < CC; ++ci) {
    float w = W_lds[h * CC * CC + ci * CC + c];
#pragma unroll
    for (int l = 0; l < LL; ++l)
      acc[l] = fmaf(xr[ci * (VV * LL) + l], w, acc[l]);
  }

  const int slab0 = h * NBL + b * LL;
#pragma unroll
  for (int l = 0; l < LL; ++l) {
    __half hv = __float2half(acc[l]);
    h_g[((size_t)(slab0 + l) * VV + v) * CC + c] = *(ushort*)&hv;
  }

  // s_src/s_dst: 192 threads cover (vp2, h2, l, which)
  if (tid < 192) {
    int which = tid & 1;
    int t2 = tid >> 1;            // 0..95
    int l = t2 % 12;
    int h2 = (t2 / 12) & 3;
    int vp2 = t2 / 48;
    float s = 0.f;
#pragma unroll
    for (int ci = 0; ci < CC; ++ci)
      s = fmaf(x_s[ci * 24 + vp2 * 12 + l], wa[h2][which][ci], s);
    int slab = h2 * NBL + b * LL + l;
    float* dp = which ? s_dst : s_src;
    dp[slab * VV + v0 + vp2] = s;
  }
}

// ---------------------------------------------------------------------------
// k_agg: 3072 blocks; XCD slot (blk&7) = (b, v-half) so each XCD's L2 holds
// one b's 48 slabs (3 MB) + half the csr. Within a slot, the index iterates
// l fastest -> the 12 writers of each output line run temporally adjacent
// on one XCD (full-line HBM writebacks). Each wave processes 4 consecutive
// v (task loop) -> 4x fewer workgroups, amortized setup.
// Per task: phase A (16 edges x 4 h; one exp per (edge,h); slots >= m hold
// ee=0,dst=0) -> per-warp LDS; phase B lane = ii(4 slots) x h(4) x cg(4):
// dwordx4 gather (8 f16 ch) + 8 fma_mix per 4 edges. Tail: xor-16/32 then
// xor-4/8, fused mean-over-h + ELU, 16 lanes write 2 dwords.
// ---------------------------------------------------------------------------
__global__ __launch_bounds__(256) void k_agg(const ushort* __restrict__ hg,
                                             const float* __restrict__ s_src,
                                             const float* __restrict__ s_dst,
                                             const int* __restrict__ cnt,
                                             const uint2* __restrict__ csr,
                                             float* __restrict__ outp) {
  __shared__ uint ed_dst[4][16];        // [warp][edge]
  __shared__ float ed_ee[4][16][HH];    // [warp][edge][h]
  const int blk = blockIdx.x;
  const int slot = blk & 7;             // XCD slot = (b, v-half)
  const int j = blk >> 3;               // 0..383, l fastest
  const int b = slot >> 1, hv = slot & 1;
  const int vc = j / 12, l = j % 12;    // vc 0..31
  const int bl = b * LL + l;
  const int warp = threadIdx.x >> 6;
  const int lane = threadIdx.x & 63;

  // phase-A role: lane = ha*16 + ia
  const int ha = lane >> 4;
  const int ia = lane & 15;
  // phase-B role: lane = ii*16 + h*4 + cg
  const int ii = lane >> 4;
  const int h = (lane >> 2) & 3;
  const int cg = lane & 3;

  const int vbase = hv * 500 + vc * 16 + warp * 4;
  const int vlim = hv * 500 + 500;

  const int slabA = ha * NBL + bl;
  const float* sdbA = s_dst + slabA * VV;
  const uint hoff = (uint)((h * NBL + bl) * (VV * CC * 2)) + (uint)(cg * 16);
  const char* hgbytes = (const char*)hg;

#pragma unroll 1
  for (int k = 0; k < 4; ++k) {
    const int v = vbase + k;
    const bool valid = (v < vlim);      // wave-uniform
    int deg = 0;
    float ssv = 0.f;
    if (valid) {
      deg = cnt[v];
      if (deg > RCAP) deg = RCAP;
      ssv = s_src[slabA * VV + v];
    }
    const int rbase = v * RCAP;

    float num[8];
#pragma unroll
    for (int q = 0; q < 8; ++q) num[q] = 0.f;
    float rs = 0.f;

    for (int base = 0; base < deg; base += 16) {
      // ---- phase A ----
      int e = base + ia;
      float eev = 0.f;
      int d = 0;
      if (e < deg) {
        uint2 ent = csr[rbase + e];
        d = (int)ent.x;
        float lv = __uint_as_float(ent.y);
        float s = ssv + sdbA[d];
        float lr = s > 0.f ? s : LALPHA * s;
        eev = __expf(-lr) * lv;
      }
      ed_ee[warp][ia][ha] = eev;
      if (ha == 0) ed_dst[warp][ia] = (uint)d;

      // ---- phase B: 4 edges x (4h x 32c) per iter ----
      int m = deg - base;
      if (m > 16) m = 16;
      int iters = (m + 3) >> 2;
      for (int t = 0; t < iters; ++t) {
        int idx = (t << 2) + ii;     // <= 15 always
        uint d2 = ed_dst[warp][idx];
        float eh = ed_ee[warp][idx][h];
        uint voff = (d2 << 6) + hoff;
        uint4 g = *(const uint4*)(hgbytes + voff);   // 8 f16 channels
        __half2 p0 = __builtin_bit_cast(__half2, g.x);
        __half2 p1 = __builtin_bit_cast(__half2, g.y);
        __half2 p2 = __builtin_bit_cast(__half2, g.z);
        __half2 p3 = __builtin_bit_cast(__half2, g.w);
        num[0] = fmaf(eh, __low2float(p0), num[0]);
        num[1] = fmaf(eh, __high2float(p0), num[1]);
        num[2] = fmaf(eh, __low2float(p1), num[2]);
        num[3] = fmaf(eh, __high2float(p1), num[3]);
        num[4] = fmaf(eh, __low2float(p2), num[4]);
        num[5] = fmaf(eh, __high2float(p2), num[5]);
        num[6] = fmaf(eh, __low2float(p3), num[6]);
        num[7] = fmaf(eh, __high2float(p3), num[7]);
        rs += eh;
      }
    }

    // reduce over edge-slots (ii): xor 16, 32
#pragma unroll
    for (int mm = 16; mm <= 32; mm <<= 1) {
#pragma unroll
      for (int q = 0; q < 8; ++q) num[q] += __shfl_xor(num[q], mm);
      rs += __shfl_xor(rs, mm);
    }
    float inv = __frcp_rn(rs);
    float val[8];
#pragma unroll
    for (int q = 0; q < 8; ++q) val[q] = num[q] * inv;
    // reduce over heads (h bits): xor 4, 8
#pragma unroll
    for (int mm = 4; mm <= 8; mm <<= 1) {
#pragma unroll
      for (int q = 0; q < 8; ++q) val[q] += __shfl_xor(val[q], mm);
    }

    if (ii == 0 && valid) {
      int j0 = 2 * h;               // lane (h,cg) writes channels cg*8+2h, +1
      float a0 = val[j0] * 0.25f;
      float a1 = val[j0 + 1] * 0.25f;
      a0 = a0 > 0.f ? a0 : expm1f(a0);
      a1 = a1 > 0.f ? a1 : expm1f(a1);
      size_t o0 = ((size_t)(b * CC + cg * 8 + j0) * VV + v) * LL + l;
      outp[o0] = a0;
      outp[o0 + (size_t)VV * LL] = a1;
    }
  }
}

// ---------------------------------------------------------------------------
extern "C" void kernel_launch(void* const* d_in, const int* in_sizes, int n_in,
                              void* d_out, int out_size, void* d_ws, size_t ws_size,
                              hipStream_t stream) {
  const float* x = (const float*)d_in[0];
  const float* W = (const float*)d_in[1];
  const float* a = (const float*)d_in[2];
  const int* ei = (const int*)d_in[3];
  const float* ev = (const float*)d_in[4];
  float* out = (float*)d_out;
  float* ws = (float*)d_ws;

  size_t o = 0;
  ushort* h_g = (ushort*)(ws + o);  o += (size_t)SS * VV * CC / 2;   // f16, 12.3 MB
  float* s_src = ws + o;            o += SS * VV;
  float* s_dst = ws + o;            o += SS * VV;
  int* cnt = (int*)(ws + o);        o += 1024;
  uint2* csr = (uint2*)(ws + o);    o += (size_t)VV * RCAP * 2;      // {dst, lv}

  hipMemsetAsync(cnt, 0, 1024 * sizeof(int), stream);

  dim3 gA(520, BB);   // x<500: h-projection; x>=500: edge scatter
  k_h<<<gA, 256, 0, stream>>>(x, W, a, h_g, s_src, s_dst, cnt, ei, ev, csr);

  k_agg<<<3072, 256, 0, stream>>>(h_g, s_src, s_dst, cnt, csr, out);
}